// Round 15
// baseline (337.103 us; speedup 1.0000x reference)
//
#include <hip/hip_runtime.h>
#include <stdint.h>

#define D_MODEL 768
#define N3      2304
#define NHEAD   8
#define DH      96
#define BATCH   8
#define SEQ     4096
#define ROWS    (BATCH*SEQ)   // 32768
#define LN_EPS  1e-5f

typedef __attribute__((ext_vector_type(8))) __bf16 bf16x8;
typedef __attribute__((ext_vector_type(4))) float f32x4;
typedef __attribute__((ext_vector_type(8))) unsigned short ushort8;
typedef __attribute__((ext_vector_type(4))) unsigned short ushort4v;

__device__ __forceinline__ unsigned short f2bf(float f) {
  union { float f; unsigned int u; } v; v.f = f;
  unsigned int r = v.u + 0x7FFFu + ((v.u >> 16) & 1u);
  return (unsigned short)(r >> 16);
}
__device__ __forceinline__ float bf2f(unsigned short u) {
  union { unsigned int u; float f; } v; v.u = ((unsigned int)u) << 16;
  return v.f;
}

#define GLOBAL_LDS16(src, dst) \
  __builtin_amdgcn_global_load_lds((const __attribute__((address_space(1))) void*)(src), \
                                   (__attribute__((address_space(3))) void*)(dst), 16, 0, 0)

#define GATE(n) do { asm volatile("s_waitcnt vmcnt(" #n ")" ::: "memory"); \
                     __builtin_amdgcn_s_barrier(); asm volatile("" ::: "memory"); } while (0)

// ---- prep: merged weight transpose (blocks 0..2303) + LayerNorm (rest) ----
__global__ __launch_bounds__(256) void prep_kernel(
    const float* __restrict__ wqkv, const float* __restrict__ wout,
    unsigned short* __restrict__ wqkvT, unsigned short* __restrict__ woutT,
    const float* __restrict__ x, const float* __restrict__ gamma,
    const float* __restrict__ beta, unsigned short* __restrict__ xn) {
  if (blockIdx.x < 2304) {
    __shared__ float tile[32][33];
    int v = blockIdx.x;
    int bx = v % 96, by = v / 96;
    const float* in; unsigned short* out; int C, c0;
    if (bx < 72) { in = wqkv; out = wqkvT; C = N3;      c0 = bx * 32; }
    else         { in = wout; out = woutT; C = D_MODEL; c0 = (bx - 72) * 32; }
    int r0 = by * 32;
    int tx = threadIdx.x & 31, ty = threadIdx.x >> 5;
    #pragma unroll
    for (int i = ty; i < 32; i += 8)
      tile[i][tx] = in[(size_t)(r0 + i) * C + c0 + tx];
    __syncthreads();
    #pragma unroll
    for (int i = ty; i < 32; i += 8)
      out[(size_t)(c0 + i) * D_MODEL + r0 + tx] = f2bf(tile[tx][i]);
    return;
  }
  int wave = threadIdx.x >> 6, lane = threadIdx.x & 63;
  int row = (blockIdx.x - 2304) * 4 + wave;
  const float* xr = x + (size_t)row * D_MODEL;
  f32x4 v[3];
  float s = 0.f, sq = 0.f;
  #pragma unroll
  for (int i = 0; i < 3; ++i) {
    v[i] = *(const f32x4*)(xr + (i * 64 + lane) * 4);
    #pragma unroll
    for (int c = 0; c < 4; ++c) { s += v[i][c]; sq += v[i][c] * v[i][c]; }
  }
  #pragma unroll
  for (int o = 32; o; o >>= 1) {
    s  += __shfl_xor(s, o, 64);
    sq += __shfl_xor(sq, o, 64);
  }
  float mu  = s * (1.f / 768.f);
  float var = sq * (1.f / 768.f) - mu * mu;
  float rs  = rsqrtf(var + LN_EPS);
  #pragma unroll
  for (int i = 0; i < 3; ++i) {
    int col = (i * 64 + lane) * 4;
    ushort4v o;
    #pragma unroll
    for (int c = 0; c < 4; ++c)
      o[c] = f2bf((v[i][c] - mu) * rs * gamma[col + c] + beta[col + c]);
    *(ushort4v*)(xn + (size_t)row * D_MODEL + col) = o;
  }
}

// ====== qkv GEMM 128x192, BK=32, 3 bufs, 2 blocks/CU, 128x48 wave tiles ======
// Grid 256 bm x 12 bn = 3072 = 6.0 even rounds of 512 slots. bn 0-3 -> Q
// row-major (elu+1); 4-7 -> K, 8-11 -> V blocked [lblk=bm][h][d][l 128].
// 5 loads/wave/tile -> GATE(5) proves tile t (FIFO). Swizzle as proven.
__global__ __launch_bounds__(256, 2) void gemm_qkv_w_kernel(
    const unsigned short* __restrict__ A, const unsigned short* __restrict__ Bt,
    unsigned short* __restrict__ qb, unsigned short* __restrict__ kT,
    unsigned short* __restrict__ vT) {
  __shared__ unsigned short As[3 * 4096];   // [buf][128][32]
  __shared__ unsigned short Bs[3 * 6144];   // [buf][192][32]
  const int K = D_MODEL, nbn = 12;
  int nwg = gridDim.x, id = blockIdx.x;
  int q8 = nwg >> 3;
  int wg = (id & 7) * q8 + (id >> 3);
  int bm = wg / nbn, bn = wg % nbn;

  const int lane = threadIdx.x & 63, wid = threadIdx.x >> 6;
  const int l15 = lane & 15, hi = lane >> 4;
  const int colS = (hi ^ ((l15 >> 1) & 3)) << 3;
  const int srow = lane >> 2;
  const int scol = ((lane & 3) ^ ((lane >> 3) & 3)) << 3;

  const unsigned short* a0 = A  + (size_t)(bm * 128 +      wid * 16 + srow) * K + scol;
  const unsigned short* a1 = A  + (size_t)(bm * 128 + 64 + wid * 16 + srow) * K + scol;
  const unsigned short* b0 = Bt + (size_t)(bn * 192 + wid * 48 +      srow) * K + scol;
  const unsigned short* b1 = Bt + (size_t)(bn * 192 + wid * 48 + 16 + srow) * K + scol;
  const unsigned short* b2 = Bt + (size_t)(bn * 192 + wid * 48 + 32 + srow) * K + scol;
  auto stage = [&](int buf, int kt) {
    GLOBAL_LDS16(a0 + kt * 32, &As[buf * 4096 +        wid * 512]);
    GLOBAL_LDS16(a1 + kt * 32, &As[buf * 4096 + 2048 + wid * 512]);
    GLOBAL_LDS16(b0 + kt * 32, &Bs[buf * 6144 + wid * 1536]);
    GLOBAL_LDS16(b1 + kt * 32, &Bs[buf * 6144 + wid * 1536 + 512]);
    GLOBAL_LDS16(b2 + kt * 32, &Bs[buf * 6144 + wid * 1536 + 1024]);
  };

  f32x4 acc[8][3];   // rows mf*16+hi*4+r (128), cols wid*48+nf*16+l15
  #pragma unroll
  for (int i = 0; i < 8; ++i)
    #pragma unroll
    for (int j = 0; j < 3; ++j) acc[i][j] = (f32x4){0.f, 0.f, 0.f, 0.f};

#define QTILE(BUF, STG) do { \
    bf16x8 af[8], bv[3]; \
    _Pragma("unroll") for (int mf = 0; mf < 8; ++mf) \
      af[mf] = *(const bf16x8*)&As[(BUF) * 4096 + (mf * 16 + l15) * 32 + colS]; \
    _Pragma("unroll") for (int nf = 0; nf < 3; ++nf) \
      bv[nf] = *(const bf16x8*)&Bs[(BUF) * 6144 + (wid * 48 + nf * 16 + l15) * 32 + colS]; \
    STG; \
    __builtin_amdgcn_s_setprio(1); \
    _Pragma("unroll") for (int mf = 0; mf < 8; ++mf) \
      _Pragma("unroll") for (int nf = 0; nf < 3; ++nf) \
        acc[mf][nf] = __builtin_amdgcn_mfma_f32_16x16x32_bf16( \
            af[mf], bv[nf], acc[mf][nf], 0, 0, 0); \
    __builtin_amdgcn_s_setprio(0); \
  } while (0)

  stage(0, 0); stage(1, 1);
  for (int it = 0; it < 7; ++it) {
    int T = 3 * it;
    GATE(5); QTILE(0, stage(2, T + 2));
    GATE(5); QTILE(1, stage(0, T + 3));
    GATE(5); QTILE(2, stage(1, T + 4));
  }
  GATE(5); QTILE(0, stage(2, 23));
  GATE(5); QTILE(1, {});
  GATE(0); QTILE(2, {});
#undef QTILE

  int r0 = bm * 128, c0 = bn * 192 + wid * 48;
  if (bn < 4) {
    #pragma unroll
    for (int mf = 0; mf < 8; ++mf)
      #pragma unroll
      for (int nf = 0; nf < 3; ++nf) {
        int col = c0 + nf * 16 + l15;
        #pragma unroll
        for (int r = 0; r < 4; ++r) {
          int row = r0 + mf * 16 + hi * 4 + r;
          float v = acc[mf][nf][r];
          v = (v > 0.f) ? v + 1.f : __expf(v);          // elu(x)+1
          qb[(size_t)row * D_MODEL + col] = f2bf(v);
        }
      }
  } else {
    const bool isK = (bn < 8);
    unsigned short* T = isK ? kT : vT;
    int cbase = c0 - (isK ? 768 : 1536);
    #pragma unroll
    for (int mf = 0; mf < 8; ++mf) {
      int ll = mf * 16 + hi * 4;
      #pragma unroll
      for (int nf = 0; nf < 3; ++nf) {
        int cc = cbase + nf * 16 + l15;
        int h = cc / 96, d = cc - h * 96;
        ushort4v pk;
        #pragma unroll
        for (int r = 0; r < 4; ++r) {
          float v = acc[mf][nf][r];
          if (isK) v = (v > 0.f) ? v + 1.f : __expf(v);  // elu(x)+1
          pk[r] = f2bf(v);
        }
        *(ushort4v*)&T[(((size_t)bm * 8 + h) * 96 + d) * 128 + ll] = pk;
      }
    }
  }
}

// ======== kv aggregation v3: 512 blocks (2/CU), shared phantom rows ======
__global__ __launch_bounds__(256) void kvagg3_kernel(
    const unsigned short* __restrict__ kT, const unsigned short* __restrict__ vT,
    float* __restrict__ kvp) {
  __shared__ unsigned short KTs[3 * 6144];   // [buf][96 d][64]
  __shared__ unsigned short VTs[3 * 6144];   // [buf][96 e][64]
  __shared__ unsigned short PH[2048];        // rows 96..127 (32 x 64)
  int bh = blockIdx.x >> 3, chunk = blockIdx.x & 7;
  int tid = threadIdx.x;
  int lane = tid & 63, wid = tid >> 6;
  int l15 = lane & 15, hi = lane >> 4;

  {
    int r = tid >> 3, sl = tid & 7;
    unsigned short val = (r == 0) ? (unsigned short)0x3F80 : (unsigned short)0;
    ushort8 v8 = {val, val, val, val, val, val, val, val};
    *(ushort8*)&PH[(r * 8 + sl) * 8] = v8;
  }
  __syncthreads();

  const int b = bh >> 3, h = bh & 7;
  auto stage = [&](int buf, int t) {
    #pragma unroll
    for (int i = 0; i < 3; ++i) {
      int sidx = i * 256 + tid;
      int row = sidx >> 3;
      int L = (sidx & 7) ^ (row & 7);
      size_t g = ((((size_t)b * 32 + chunk * 4 + (t >> 1)) * 8 + h) * 96 + row) * 128
               + (t & 1) * 64 + L * 8;
      GLOBAL_LDS16(kT + g, &KTs[buf * 6144 + (i * 256 + wid * 64) * 8]);
      GLOBAL_LDS16(vT + g, &VTs[buf * 6144 + (i * 256 + wid * 64) * 8]);
    }
  };

  f32x4 acc[6][2];
  #pragma unroll
  for (int i = 0; i < 6; ++i)
    #pragma unroll
    for (int j = 0; j < 2; ++j) acc[i][j] = (f32x4){0.f, 0.f, 0.f, 0.f};

#define KVTILE(BUF) do { \
    _Pragma("unroll") for (int kq = 0; kq < 2; ++kq) { \
      bf16x8 af[6], bv[2]; \
      _Pragma("unroll") for (int mf = 0; mf < 6; ++mf) { \
        int row = mf * 16 + l15; \
        af[mf] = *(const bf16x8*)&KTs[(BUF) * 6144 + row * 64 + ((kq * 4 + hi) ^ (row & 7)) * 8]; } \
      if (wid < 3) { \
        _Pragma("unroll") for (int nf = 0; nf < 2; ++nf) { \
          int row = wid * 32 + nf * 16 + l15; \
          bv[nf] = *(const bf16x8*)&VTs[(BUF) * 6144 + row * 64 + ((kq * 4 + hi) ^ (row & 7)) * 8]; } \
      } else { \
        _Pragma("unroll") for (int nf = 0; nf < 2; ++nf) { \
          int row = nf * 16 + l15; \
          bv[nf] = *(const bf16x8*)&PH[row * 64 + ((kq * 4 + hi) ^ ((row + 96) & 7)) * 8]; } \
      } \
      __builtin_amdgcn_s_setprio(1); \
      _Pragma("unroll") for (int mf = 0; mf < 6; ++mf) \
        _Pragma("unroll") for (int nf = 0; nf < 2; ++nf) \
          acc[mf][nf] = __builtin_amdgcn_mfma_f32_16x16x32_bf16( \
              af[mf], bv[nf], acc[mf][nf], 0, 0, 0); \
      __builtin_amdgcn_s_setprio(0); \
    } } while (0)

  stage(0, 0); stage(1, 1);
  for (int t = 0; t < 6; ++t) {
    stage((t + 2) % 3, t + 2);
    GATE(12);
    KVTILE(t % 3);
  }
  GATE(6); KVTILE(0);
  GATE(0); KVTILE(1);
#undef KVTILE

  float* outp = kvp + ((size_t)bh * 8 + chunk) * (96 * 112);
  #pragma unroll
  for (int nf = 0; nf < 2; ++nf) {
    int e = wid * 32 + nf * 16 + l15;
    if (e < 112) {
      #pragma unroll
      for (int mf = 0; mf < 6; ++mf)
        #pragma unroll
        for (int r = 0; r < 4; ++r) {
          int d = mf * 16 + hi * 4 + r;
          outp[d * 112 + e] = acc[mf][nf][r];
        }
    }
  }
}

// ---- mid2: merged M-precompute w/ local kvp reduction (blocks 0..191)
//           + q-scale w/ local ksum reduction (blocks 192..703) ----
__global__ __launch_bounds__(256) void mid2_kernel(
    const float* __restrict__ kvp, const unsigned short* __restrict__ woutT,
    unsigned short* __restrict__ Mt,
    const unsigned short* __restrict__ qb, unsigned short* __restrict__ qhat) {
  if (blockIdx.x < 192) {
    int bx = blockIdx.x;
    int cb = bx % 3, h = (bx / 3) % 8, b = bx / 24;
    int bh = b * 8 + h;
    const int lane = threadIdx.x & 63, wid = threadIdx.x >> 6;
    const int l15 = lane & 15, hi = lane >> 4;
    const float* kp = kvp + (size_t)bh * 8 * 96 * 112;

    f32x4 acc[6][4];
    #pragma unroll
    for (int i = 0; i < 6; ++i)
      #pragma unroll
      for (int j = 0; j < 4; ++j) acc[i][j] = (f32x4){0.f, 0.f, 0.f, 0.f};

    #pragma unroll
    for (int kq = 0; kq < 3; ++kq) {
      int e0 = kq * 32 + hi * 8;
      bf16x8 af[6], bv[4];
      #pragma unroll
      for (int rf = 0; rf < 6; ++rf) {
        int d = rf * 16 + l15;
        f32x4 sa = {0.f, 0.f, 0.f, 0.f}, sb = {0.f, 0.f, 0.f, 0.f};
        #pragma unroll
        for (int c = 0; c < 8; ++c) {
          const float* p = kp + ((size_t)c * 96 + d) * 112 + e0;
          sa += *(const f32x4*)p;
          sb += *(const f32x4*)(p + 4);
        }
        ushort8 tmp;                        // FIX: bit-pack, then reinterpret
        #pragma unroll
        for (int j = 0; j < 4; ++j) { tmp[j] = f2bf(sa[j]); tmp[4 + j] = f2bf(sb[j]); }
        af[rf] = *(const bf16x8*)&tmp;
      }
      #pragma unroll
      for (int cf = 0; cf < 4; ++cf) {
        int c = cb * 256 + wid * 64 + cf * 16 + l15;
        bv[cf] = *(const bf16x8*)&woutT[(size_t)c * 768 + h * 96 + e0];
      }
      #pragma unroll
      for (int rf = 0; rf < 6; ++rf)
        #pragma unroll
        for (int cf = 0; cf < 4; ++cf)
          acc[rf][cf] = __builtin_amdgcn_mfma_f32_16x16x32_bf16(
              af[rf], bv[cf], acc[rf][cf], 0, 0, 0);
    }

    #pragma unroll
    for (int rf = 0; rf < 6; ++rf) {
      int hd = h * 96 + rf * 16 + hi * 4;
      #pragma unroll
      for (int cf = 0; cf < 4; ++cf) {
        int c = cb * 256 + wid * 64 + cf * 16 + l15;
        ushort4v pk;
        #pragma unroll
        for (int r = 0; r < 4; ++r) pk[r] = f2bf(acc[rf][cf][r]);
        *(ushort4v*)&Mt[(size_t)b * 589824 + (size_t)c * 768 + hd] = pk;
      }
    }
    return;
  }
  // ---- scale: qhat = q / max(q_h . ksum_bh, 1e-6); ksum reduced locally ----
  __shared__ float ks[8][96];
  int tid = threadIdx.x;
  int row0 = (blockIdx.x - 192) * 64;
  int b = row0 >> 12;
  #pragma unroll
  for (int i = 0; i < 3; ++i) {
    int idx = i * 256 + tid;
    if (idx < 768) {
      int h = idx / 96, d = idx % 96;
      const float* p = kvp + (((size_t)(b * 8 + h) * 8) * 96 + d) * 112 + 96;
      float s = 0.f;
      #pragma unroll
      for (int c = 0; c < 8; ++c) s += p[(size_t)c * 96 * 112];
      ks[h][d] = s;
    }
  }
  __syncthreads();

  int row = row0 + (tid >> 2), seg = tid & 3;
  size_t base = (size_t)row * D_MODEL + seg * 192;
  ushort8 qreg[24];
  #pragma unroll
  for (int c = 0; c < 24; ++c)
    qreg[c] = *(const ushort8*)(qb + base + c * 8);

  float inv[2];
  #pragma unroll
  for (int hh = 0; hh < 2; ++hh) {
    int h = seg * 2 + hh;
    float n = 0.f;
    #pragma unroll
    for (int c = 0; c < 12; ++c)
      #pragma unroll
      for (int j = 0; j < 8; ++j)
        n += bf2f(qreg[hh * 12 + c][j]) * ks[h][c * 8 + j];
    inv[hh] = 1.f / fmaxf(n, 1e-6f);
  }
  #pragma unroll
  for (int c = 0; c < 24; ++c) {
    float sc = inv[c / 12];
    ushort8 o;
    #pragma unroll
    for (int j = 0; j < 8; ++j) o[j] = f2bf(bf2f(qreg[c][j]) * sc);
    *(ushort8*)(qhat + base + c * 8) = o;
  }
}

// ====== final GEMM 128x192: out = qhat @ Mt_b^T + x (batched) ======
// Grid 256 bm x 4 bn = 1024 = 2.0 even rounds of 512 slots.
__global__ __launch_bounds__(256, 2) void gemm_fin_kernel(
    const unsigned short* __restrict__ A, const unsigned short* __restrict__ MtAll,
    const float* __restrict__ resid, float* __restrict__ Cf) {
  __shared__ unsigned short As[3 * 4096];   // [buf][128][32]
  __shared__ unsigned short Bs[3 * 6144];   // [buf][192][32]
  const int K = D_MODEL, nbn = 4;
  int nwg = gridDim.x, id = blockIdx.x;
  int q8 = nwg >> 3;
  int wg = (id & 7) * q8 + (id >> 3);
  int bm = wg / nbn, bn = wg % nbn;
  const unsigned short* Bt = MtAll + (size_t)(bm >> 5) * 589824;  // batch b = bm/32

  const int lane = threadIdx.x & 63, wid = threadIdx.x >> 6;
  const int l15 = lane & 15, hi = lane >> 4;
  const int colS = (hi ^ ((l15 >> 1) & 3)) << 3;
  const int srow = lane >> 2;
  const int scol = ((lane & 3) ^ ((lane >> 3) & 3)) << 3;

  const unsigned short* a0 = A  + (size_t)(bm * 128 +      wid * 16 + srow) * K + scol;
  const unsigned short* a1 = A  + (size_t)(bm * 128 + 64 + wid * 16 + srow) * K + scol;
  const unsigned short* b0 = Bt + (size_t)(bn * 192 + wid * 48 +      srow) * K + scol;
  const unsigned short* b1 = Bt + (size_t)(bn * 192 + wid * 48 + 16 + srow) * K + scol;
  const unsigned short* b2 = Bt + (size_t)(bn * 192 + wid * 48 + 32 + srow) * K + scol;
  auto stage = [&](int buf, int kt) {
    GLOBAL_LDS16(a0 + kt * 32, &As[buf * 4096 +        wid * 512]);
    GLOBAL_LDS16(a1 + kt * 32, &As[buf * 4096 + 2048 + wid * 512]);
    GLOBAL_LDS16(b0 + kt * 32, &Bs[buf * 6144 + wid * 1536]);
    GLOBAL_LDS16(b1 + kt * 32, &Bs[buf * 6144 + wid * 1536 + 512]);
    GLOBAL_LDS16(b2 + kt * 32, &Bs[buf * 6144 + wid * 1536 + 1024]);
  };

  f32x4 acc[8][3];
  #pragma unroll
  for (int i = 0; i < 8; ++i)
    #pragma unroll
    for (int j = 0; j < 3; ++j) acc[i][j] = (f32x4){0.f, 0.f, 0.f, 0.f};

#define FTILE(BUF, STG) do { \
    bf16x8 af[8], bv[3]; \
    _Pragma("unroll") for (int mf = 0; mf < 8; ++mf) \
      af[mf] = *(const bf16x8*)&As[(BUF) * 4096 + (mf * 16 + l15) * 32 + colS]; \
    _Pragma("unroll") for (int nf = 0; nf < 3; ++nf) \
      bv[nf] = *(const bf16x8*)&Bs[(BUF) * 6144 + (wid * 48 + nf * 16 + l15) * 32 + colS]; \
    STG; \
    __builtin_amdgcn_s_setprio(1); \
    _Pragma("unroll") for (int mf = 0; mf < 8; ++mf) \
      _Pragma("unroll") for (int nf = 0; nf < 3; ++nf) \
        acc[mf][nf] = __builtin_amdgcn_mfma_f32_16x16x32_bf16( \
            af[mf], bv[nf], acc[mf][nf], 0, 0, 0); \
    __builtin_amdgcn_s_setprio(0); \
  } while (0)

  stage(0, 0); stage(1, 1);
  for (int it = 0; it < 7; ++it) {
    int T = 3 * it;
    GATE(5); FTILE(0, stage(2, T + 2));
    GATE(5); FTILE(1, stage(0, T + 3));
    GATE(5); FTILE(2, stage(1, T + 4));
  }
  GATE(5); FTILE(0, stage(2, 23));
  GATE(5); FTILE(1, {});
  GATE(0); FTILE(2, {});
#undef FTILE

  int r0 = bm * 128, c0 = bn * 192 + wid * 48;
  #pragma unroll
  for (int mf = 0; mf < 8; ++mf)
    #pragma unroll
    for (int nf = 0; nf < 3; ++nf) {
      int col = c0 + nf * 16 + l15;
      #pragma unroll
      for (int r = 0; r < 4; ++r) {
        int row = r0 + mf * 16 + hi * 4 + r;
        Cf[(size_t)row * D_MODEL + col] =
            acc[mf][nf][r] + resid[(size_t)row * D_MODEL + col];
      }
    }
}

extern "C" void kernel_launch(void* const* d_in, const int* in_sizes, int n_in,
                              void* d_out, int out_size, void* d_ws, size_t ws_size,
                              hipStream_t stream) {
  const float* x     = (const float*)d_in[0];
  const float* gamma = (const float*)d_in[1];
  const float* beta  = (const float*)d_in[2];
  const float* w_qkv = (const float*)d_in[3];
  const float* w_out = (const float*)d_in[4];
  float* out = (float*)d_out;

  char* ws = (char*)d_ws;
  size_t off = 0;
  auto alloc = [&](size_t bytes) -> void* {
    void* p = ws + off; off += (bytes + 255) & ~(size_t)255; return p;
  };
  unsigned short* xn    = (unsigned short*)alloc((size_t)ROWS * D_MODEL * 2);  // reused as qhat
  unsigned short* qb    = (unsigned short*)alloc((size_t)ROWS * D_MODEL * 2);
  unsigned short* kTb   = (unsigned short*)alloc((size_t)64 * 96 * SEQ * 2);
  unsigned short* vTb   = (unsigned short*)alloc((size_t)64 * 96 * SEQ * 2);
  unsigned short* wqkvT = (unsigned short*)alloc((size_t)N3 * D_MODEL * 2);
  unsigned short* woutT = (unsigned short*)alloc((size_t)D_MODEL * D_MODEL * 2);
  float* kvp            = (float*)alloc((size_t)512 * 96 * 112 * 4);
  unsigned short* Mt    = (unsigned short*)alloc((size_t)BATCH * 768 * 768 * 2);

  prep_kernel<<<2304 + ROWS / 4, 256, 0, stream>>>(w_qkv, w_out, wqkvT, woutT,
                                                   x, gamma, beta, xn);
  gemm_qkv_w_kernel<<<(ROWS / 128) * (N3 / 192), 256, 0, stream>>>(xn, wqkvT, qb, kTb, vTb);
  kvagg3_kernel<<<512, 256, 0, stream>>>(kTb, vTb, kvp);
  mid2_kernel<<<192 + ROWS / 64, 256, 0, stream>>>(kvp, woutT, Mt, qb, xn);
  gemm_fin_kernel<<<(ROWS / 128) * 4, 256, 0, stream>>>(xn, Mt, x, out);
}

// Round 16
// 311.714 us; speedup vs baseline: 1.0815x; 1.0815x over previous
//
#include <hip/hip_runtime.h>
#include <stdint.h>

#define D_MODEL 768
#define N3      2304
#define NHEAD   8
#define DH      96
#define BATCH   8
#define SEQ     4096
#define ROWS    (BATCH*SEQ)   // 32768
#define LN_EPS  1e-5f

typedef __attribute__((ext_vector_type(8))) __bf16 bf16x8;
typedef __attribute__((ext_vector_type(4))) float f32x4;
typedef __attribute__((ext_vector_type(8))) unsigned short ushort8;
typedef __attribute__((ext_vector_type(4))) unsigned short ushort4v;

__device__ __forceinline__ unsigned short f2bf(float f) {
  union { float f; unsigned int u; } v; v.f = f;
  unsigned int r = v.u + 0x7FFFu + ((v.u >> 16) & 1u);
  return (unsigned short)(r >> 16);
}
__device__ __forceinline__ float bf2f(unsigned short u) {
  union { unsigned int u; float f; } v; v.u = ((unsigned int)u) << 16;
  return v.f;
}

#define GLOBAL_LDS16(src, dst) \
  __builtin_amdgcn_global_load_lds((const __attribute__((address_space(1))) void*)(src), \
                                   (__attribute__((address_space(3))) void*)(dst), 16, 0, 0)

#define GATE(n) do { asm volatile("s_waitcnt vmcnt(" #n ")" ::: "memory"); \
                     __builtin_amdgcn_s_barrier(); asm volatile("" ::: "memory"); } while (0)

// ---- prep: merged weight transpose (blocks 0..2303) + LayerNorm (rest) ----
__global__ __launch_bounds__(256) void prep_kernel(
    const float* __restrict__ wqkv, const float* __restrict__ wout,
    unsigned short* __restrict__ wqkvT, unsigned short* __restrict__ woutT,
    const float* __restrict__ x, const float* __restrict__ gamma,
    const float* __restrict__ beta, unsigned short* __restrict__ xn) {
  if (blockIdx.x < 2304) {
    __shared__ float tile[32][33];
    int v = blockIdx.x;
    int bx = v % 96, by = v / 96;
    const float* in; unsigned short* out; int C, c0;
    if (bx < 72) { in = wqkv; out = wqkvT; C = N3;      c0 = bx * 32; }
    else         { in = wout; out = woutT; C = D_MODEL; c0 = (bx - 72) * 32; }
    int r0 = by * 32;
    int tx = threadIdx.x & 31, ty = threadIdx.x >> 5;
    #pragma unroll
    for (int i = ty; i < 32; i += 8)
      tile[i][tx] = in[(size_t)(r0 + i) * C + c0 + tx];
    __syncthreads();
    #pragma unroll
    for (int i = ty; i < 32; i += 8)
      out[(size_t)(c0 + i) * D_MODEL + r0 + tx] = f2bf(tile[tx][i]);
    return;
  }
  int wave = threadIdx.x >> 6, lane = threadIdx.x & 63;
  int row = (blockIdx.x - 2304) * 4 + wave;
  const float* xr = x + (size_t)row * D_MODEL;
  f32x4 v[3];
  float s = 0.f, sq = 0.f;
  #pragma unroll
  for (int i = 0; i < 3; ++i) {
    v[i] = *(const f32x4*)(xr + (i * 64 + lane) * 4);
    #pragma unroll
    for (int c = 0; c < 4; ++c) { s += v[i][c]; sq += v[i][c] * v[i][c]; }
  }
  #pragma unroll
  for (int o = 32; o; o >>= 1) {
    s  += __shfl_xor(s, o, 64);
    sq += __shfl_xor(sq, o, 64);
  }
  float mu  = s * (1.f / 768.f);
  float var = sq * (1.f / 768.f) - mu * mu;
  float rs  = rsqrtf(var + LN_EPS);
  #pragma unroll
  for (int i = 0; i < 3; ++i) {
    int col = (i * 64 + lane) * 4;
    ushort4v o;
    #pragma unroll
    for (int c = 0; c < 4; ++c)
      o[c] = f2bf((v[i][c] - mu) * rs * gamma[col + c] + beta[col + c]);
    *(ushort4v*)(xn + (size_t)row * D_MODEL + col) = o;
  }
}

// ====== qkv GEMM 128x256, BK=32, 3 bufs, 2 blocks/CU, 128x64 wave tiles ======
// (R11/R13 best). bn 0-2 -> Q row-major (elu+1); 3-5 -> K, 6-8 -> V blocked
// [lblk=bm][h][d][l 128].
__global__ __launch_bounds__(256, 2) void gemm_qkv_w_kernel(
    const unsigned short* __restrict__ A, const unsigned short* __restrict__ Bt,
    unsigned short* __restrict__ qb, unsigned short* __restrict__ kT,
    unsigned short* __restrict__ vT) {
  __shared__ unsigned short As[3 * 4096];   // [buf][128][32]
  __shared__ unsigned short Bs[3 * 8192];   // [buf][256][32]
  const int K = D_MODEL, nbn = 9;
  int nwg = gridDim.x, id = blockIdx.x;
  int q8 = nwg >> 3;
  int wg = (id & 7) * q8 + (id >> 3);
  int bm = wg / nbn, bn = wg % nbn;

  const int lane = threadIdx.x & 63, wid = threadIdx.x >> 6;
  const int wn = wid;
  const int l15 = lane & 15, hi = lane >> 4;
  const int colS = (hi ^ ((l15 >> 1) & 3)) << 3;
  const int srow = lane >> 2;
  const int scol = ((lane & 3) ^ ((lane >> 3) & 3)) << 3;

  const unsigned short* a0 = A  + (size_t)(bm * 128 +      wid * 16 + srow) * K + scol;
  const unsigned short* a1 = A  + (size_t)(bm * 128 + 64 + wid * 16 + srow) * K + scol;
  const unsigned short* b0 = Bt + (size_t)(bn * 256 + wid * 64 +      srow) * K + scol;
  const unsigned short* b1 = Bt + (size_t)(bn * 256 + wid * 64 + 16 + srow) * K + scol;
  const unsigned short* b2 = Bt + (size_t)(bn * 256 + wid * 64 + 32 + srow) * K + scol;
  const unsigned short* b3 = Bt + (size_t)(bn * 256 + wid * 64 + 48 + srow) * K + scol;
  auto stage = [&](int buf, int kt) {
    GLOBAL_LDS16(a0 + kt * 32, &As[buf * 4096 +        wid * 512]);
    GLOBAL_LDS16(a1 + kt * 32, &As[buf * 4096 + 2048 + wid * 512]);
    GLOBAL_LDS16(b0 + kt * 32, &Bs[buf * 8192 + wid * 2048]);
    GLOBAL_LDS16(b1 + kt * 32, &Bs[buf * 8192 + wid * 2048 + 512]);
    GLOBAL_LDS16(b2 + kt * 32, &Bs[buf * 8192 + wid * 2048 + 1024]);
    GLOBAL_LDS16(b3 + kt * 32, &Bs[buf * 8192 + wid * 2048 + 1536]);
  };

  f32x4 acc[8][4];
  #pragma unroll
  for (int i = 0; i < 8; ++i)
    #pragma unroll
    for (int j = 0; j < 4; ++j) acc[i][j] = (f32x4){0.f, 0.f, 0.f, 0.f};

#define QTILE(BUF, STG) do { \
    bf16x8 af[8], bv[4]; \
    _Pragma("unroll") for (int mf = 0; mf < 8; ++mf) \
      af[mf] = *(const bf16x8*)&As[(BUF) * 4096 + (mf * 16 + l15) * 32 + colS]; \
    _Pragma("unroll") for (int nf = 0; nf < 4; ++nf) \
      bv[nf] = *(const bf16x8*)&Bs[(BUF) * 8192 + (wn * 64 + nf * 16 + l15) * 32 + colS]; \
    STG; \
    __builtin_amdgcn_s_setprio(1); \
    _Pragma("unroll") for (int mf = 0; mf < 8; ++mf) \
      _Pragma("unroll") for (int nf = 0; nf < 4; ++nf) \
        acc[mf][nf] = __builtin_amdgcn_mfma_f32_16x16x32_bf16( \
            af[mf], bv[nf], acc[mf][nf], 0, 0, 0); \
    __builtin_amdgcn_s_setprio(0); \
  } while (0)

  stage(0, 0); stage(1, 1);
  for (int it = 0; it < 7; ++it) {
    int T = 3 * it;
    GATE(6); QTILE(0, stage(2, T + 2));
    GATE(6); QTILE(1, stage(0, T + 3));
    GATE(6); QTILE(2, stage(1, T + 4));
  }
  GATE(6); QTILE(0, stage(2, 23));
  GATE(6); QTILE(1, {});
  GATE(0); QTILE(2, {});
#undef QTILE

  int r0 = bm * 128, c0 = bn * 256 + wn * 64;
  if (bn < 3) {
    #pragma unroll
    for (int mf = 0; mf < 8; ++mf)
      #pragma unroll
      for (int nf = 0; nf < 4; ++nf) {
        int col = c0 + nf * 16 + l15;
        #pragma unroll
        for (int r = 0; r < 4; ++r) {
          int row = r0 + mf * 16 + hi * 4 + r;
          float v = acc[mf][nf][r];
          v = (v > 0.f) ? v + 1.f : __expf(v);          // elu(x)+1
          qb[(size_t)row * D_MODEL + col] = f2bf(v);
        }
      }
  } else {
    const bool isK = (bn < 6);
    unsigned short* T = isK ? kT : vT;
    int cbase = c0 - (isK ? 768 : 1536);
    #pragma unroll
    for (int mf = 0; mf < 8; ++mf) {
      int ll = mf * 16 + hi * 4;
      #pragma unroll
      for (int nf = 0; nf < 4; ++nf) {
        int cc = cbase + nf * 16 + l15;
        int h = cc / 96, d = cc - h * 96;
        ushort4v pk;
        #pragma unroll
        for (int r = 0; r < 4; ++r) {
          float v = acc[mf][nf][r];
          if (isK) v = (v > 0.f) ? v + 1.f : __expf(v);  // elu(x)+1
          pk[r] = f2bf(v);
        }
        *(ushort4v*)&T[(((size_t)bm * 8 + h) * 96 + d) * 128 + ll] = pk;
      }
    }
  }
}

// ======== kv aggregation v3: 512 blocks (2/CU), shared phantom rows ======
__global__ __launch_bounds__(256) void kvagg3_kernel(
    const unsigned short* __restrict__ kT, const unsigned short* __restrict__ vT,
    float* __restrict__ kvp) {
  __shared__ unsigned short KTs[3 * 6144];   // [buf][96 d][64]
  __shared__ unsigned short VTs[3 * 6144];   // [buf][96 e][64]
  __shared__ unsigned short PH[2048];        // rows 96..127 (32 x 64)
  int bh = blockIdx.x >> 3, chunk = blockIdx.x & 7;
  int tid = threadIdx.x;
  int lane = tid & 63, wid = tid >> 6;
  int l15 = lane & 15, hi = lane >> 4;

  {
    int r = tid >> 3, sl = tid & 7;
    unsigned short val = (r == 0) ? (unsigned short)0x3F80 : (unsigned short)0;
    ushort8 v8 = {val, val, val, val, val, val, val, val};
    *(ushort8*)&PH[(r * 8 + sl) * 8] = v8;
  }
  __syncthreads();

  const int b = bh >> 3, h = bh & 7;
  auto stage = [&](int buf, int t) {
    #pragma unroll
    for (int i = 0; i < 3; ++i) {
      int sidx = i * 256 + tid;
      int row = sidx >> 3;
      int L = (sidx & 7) ^ (row & 7);
      size_t g = ((((size_t)b * 32 + chunk * 4 + (t >> 1)) * 8 + h) * 96 + row) * 128
               + (t & 1) * 64 + L * 8;
      GLOBAL_LDS16(kT + g, &KTs[buf * 6144 + (i * 256 + wid * 64) * 8]);
      GLOBAL_LDS16(vT + g, &VTs[buf * 6144 + (i * 256 + wid * 64) * 8]);
    }
  };

  f32x4 acc[6][2];
  #pragma unroll
  for (int i = 0; i < 6; ++i)
    #pragma unroll
    for (int j = 0; j < 2; ++j) acc[i][j] = (f32x4){0.f, 0.f, 0.f, 0.f};

#define KVTILE(BUF) do { \
    _Pragma("unroll") for (int kq = 0; kq < 2; ++kq) { \
      bf16x8 af[6], bv[2]; \
      _Pragma("unroll") for (int mf = 0; mf < 6; ++mf) { \
        int row = mf * 16 + l15; \
        af[mf] = *(const bf16x8*)&KTs[(BUF) * 6144 + row * 64 + ((kq * 4 + hi) ^ (row & 7)) * 8]; } \
      if (wid < 3) { \
        _Pragma("unroll") for (int nf = 0; nf < 2; ++nf) { \
          int row = wid * 32 + nf * 16 + l15; \
          bv[nf] = *(const bf16x8*)&VTs[(BUF) * 6144 + row * 64 + ((kq * 4 + hi) ^ (row & 7)) * 8]; } \
      } else { \
        _Pragma("unroll") for (int nf = 0; nf < 2; ++nf) { \
          int row = nf * 16 + l15; \
          bv[nf] = *(const bf16x8*)&PH[row * 64 + ((kq * 4 + hi) ^ ((row + 96) & 7)) * 8]; } \
      } \
      __builtin_amdgcn_s_setprio(1); \
      _Pragma("unroll") for (int mf = 0; mf < 6; ++mf) \
        _Pragma("unroll") for (int nf = 0; nf < 2; ++nf) \
          acc[mf][nf] = __builtin_amdgcn_mfma_f32_16x16x32_bf16( \
              af[mf], bv[nf], acc[mf][nf], 0, 0, 0); \
      __builtin_amdgcn_s_setprio(0); \
    } } while (0)

  stage(0, 0); stage(1, 1);
  for (int t = 0; t < 6; ++t) {
    stage((t + 2) % 3, t + 2);
    GATE(12);
    KVTILE(t % 3);
  }
  GATE(6); KVTILE(0);
  GATE(0); KVTILE(1);
#undef KVTILE

  float* outp = kvp + ((size_t)bh * 8 + chunk) * (96 * 112);
  #pragma unroll
  for (int nf = 0; nf < 2; ++nf) {
    int e = wid * 32 + nf * 16 + l15;
    if (e < 112) {
      #pragma unroll
      for (int mf = 0; mf < 6; ++mf)
        #pragma unroll
        for (int r = 0; r < 4; ++r) {
          int d = mf * 16 + hi * 4 + r;
          outp[d * 112 + e] = acc[mf][nf][r];
        }
    }
  }
}

// ---- reduce 8 partials -> kvN bf16 [64][96][96] + ksumf fp32 [64][96] ----
__global__ __launch_bounds__(256) void kvreduce2_kernel(
    const float* __restrict__ kvp, unsigned short* __restrict__ kvN,
    float* __restrict__ ksumf) {
  int idx = blockIdx.x * 256 + threadIdx.x;
  if (idx >= 64 * 96 * 112) return;
  int e = idx % 112;
  int d = (idx / 112) % 96;
  int bh = idx / (112 * 96);
  float s = 0.f;
  #pragma unroll
  for (int c = 0; c < 8; ++c)
    s += kvp[(((size_t)bh * 8 + c) * 96 + d) * 112 + e];
  if (e < 96)       kvN[((size_t)bh * 96 + d) * 96 + e] = f2bf(s);
  else if (e == 96) ksumf[(size_t)bh * 96 + d] = s;
}

// ---- mid: merged M-precompute (blocks 0..191) + q-scale (blocks 192..703) ----
__global__ __launch_bounds__(256) void mid_kernel(
    const unsigned short* __restrict__ kvN, const unsigned short* __restrict__ woutT,
    unsigned short* __restrict__ Mt,
    const unsigned short* __restrict__ qb, const float* __restrict__ ksumf,
    unsigned short* __restrict__ qhat) {
  if (blockIdx.x < 192) {
    int bx = blockIdx.x;
    int cb = bx % 3, h = (bx / 3) % 8, b = bx / 24;
    int bh = b * 8 + h;
    const int lane = threadIdx.x & 63, wid = threadIdx.x >> 6;
    const int l15 = lane & 15, hi = lane >> 4;

    f32x4 acc[6][4];
    #pragma unroll
    for (int i = 0; i < 6; ++i)
      #pragma unroll
      for (int j = 0; j < 4; ++j) acc[i][j] = (f32x4){0.f, 0.f, 0.f, 0.f};

    #pragma unroll
    for (int kq = 0; kq < 3; ++kq) {
      int e = kq * 32 + hi * 8;
      bf16x8 af[6], bv[4];
      #pragma unroll
      for (int rf = 0; rf < 6; ++rf) {
        int d = rf * 16 + l15;
        af[rf] = *(const bf16x8*)&kvN[((size_t)bh * 96 + d) * 96 + e];
      }
      #pragma unroll
      for (int cf = 0; cf < 4; ++cf) {
        int c = cb * 256 + wid * 64 + cf * 16 + l15;
        bv[cf] = *(const bf16x8*)&woutT[(size_t)c * 768 + h * 96 + e];
      }
      #pragma unroll
      for (int rf = 0; rf < 6; ++rf)
        #pragma unroll
        for (int cf = 0; cf < 4; ++cf)
          acc[rf][cf] = __builtin_amdgcn_mfma_f32_16x16x32_bf16(
              af[rf], bv[cf], acc[rf][cf], 0, 0, 0);
    }

    #pragma unroll
    for (int rf = 0; rf < 6; ++rf) {
      int hd = h * 96 + rf * 16 + hi * 4;
      #pragma unroll
      for (int cf = 0; cf < 4; ++cf) {
        int c = cb * 256 + wid * 64 + cf * 16 + l15;
        ushort4v pk;
        #pragma unroll
        for (int r = 0; r < 4; ++r) pk[r] = f2bf(acc[rf][cf][r]);
        *(ushort4v*)&Mt[(size_t)b * 589824 + (size_t)c * 768 + hd] = pk;
      }
    }
    return;
  }
  // ---- scale: qhat = q / max(q_h . ksum_bh, 1e-6) ----
  __shared__ float ks[8][96];
  int tid = threadIdx.x;
  int row0 = (blockIdx.x - 192) * 64;
  int b = row0 >> 12;
  #pragma unroll
  for (int i = 0; i < 3; ++i) {
    int idx = i * 256 + tid;
    if (idx < 768) ks[idx / 96][idx % 96] = ksumf[(size_t)b * 768 + idx];
  }
  __syncthreads();

  int row = row0 + (tid >> 2), seg = tid & 3;
  size_t base = (size_t)row * D_MODEL + seg * 192;
  ushort8 qreg[24];
  #pragma unroll
  for (int c = 0; c < 24; ++c)
    qreg[c] = *(const ushort8*)(qb + base + c * 8);

  float inv[2];
  #pragma unroll
  for (int hh = 0; hh < 2; ++hh) {
    int h = seg * 2 + hh;
    float n = 0.f;
    #pragma unroll
    for (int c = 0; c < 12; ++c)
      #pragma unroll
      for (int j = 0; j < 8; ++j)
        n += bf2f(qreg[hh * 12 + c][j]) * ks[h][c * 8 + j];
    inv[hh] = 1.f / fmaxf(n, 1e-6f);
  }
  #pragma unroll
  for (int c = 0; c < 24; ++c) {
    float sc = inv[c / 12];
    ushort8 o;
    #pragma unroll
    for (int j = 0; j < 8; ++j) o[j] = f2bf(bf2f(qreg[c][j]) * sc);
    *(ushort8*)(qhat + base + c * 8) = o;
  }
}

// ====== final GEMM 128x256 wide-tile: out = qhat @ Mt_b^T + x (batched) ======
__global__ __launch_bounds__(256, 2) void gemm_fin_kernel(
    const unsigned short* __restrict__ A, const unsigned short* __restrict__ MtAll,
    const float* __restrict__ resid, float* __restrict__ Cf) {
  __shared__ unsigned short As[3 * 4096];   // [buf][128][32]
  __shared__ unsigned short Bs[3 * 8192];   // [buf][256][32]
  const int K = D_MODEL, nbn = 3;
  int nwg = gridDim.x, id = blockIdx.x;
  int q8 = nwg >> 3;
  int wg = (id & 7) * q8 + (id >> 3);
  int bm = wg / nbn, bn = wg % nbn;
  const unsigned short* Bt = MtAll + (size_t)(bm >> 5) * 589824;  // batch b = bm/32

  const int lane = threadIdx.x & 63, wid = threadIdx.x >> 6;
  const int wn = wid;
  const int l15 = lane & 15, hi = lane >> 4;
  const int colS = (hi ^ ((l15 >> 1) & 3)) << 3;
  const int srow = lane >> 2;
  const int scol = ((lane & 3) ^ ((lane >> 3) & 3)) << 3;

  const unsigned short* a0 = A  + (size_t)(bm * 128 +      wid * 16 + srow) * K + scol;
  const unsigned short* a1 = A  + (size_t)(bm * 128 + 64 + wid * 16 + srow) * K + scol;
  const unsigned short* b0 = Bt + (size_t)(bn * 256 + wid * 64 +      srow) * K + scol;
  const unsigned short* b1 = Bt + (size_t)(bn * 256 + wid * 64 + 16 + srow) * K + scol;
  const unsigned short* b2 = Bt + (size_t)(bn * 256 + wid * 64 + 32 + srow) * K + scol;
  const unsigned short* b3 = Bt + (size_t)(bn * 256 + wid * 64 + 48 + srow) * K + scol;
  auto stage = [&](int buf, int kt) {
    GLOBAL_LDS16(a0 + kt * 32, &As[buf * 4096 +        wid * 512]);
    GLOBAL_LDS16(a1 + kt * 32, &As[buf * 4096 + 2048 + wid * 512]);
    GLOBAL_LDS16(b0 + kt * 32, &Bs[buf * 8192 + wid * 2048]);
    GLOBAL_LDS16(b1 + kt * 32, &Bs[buf * 8192 + wid * 2048 + 512]);
    GLOBAL_LDS16(b2 + kt * 32, &Bs[buf * 8192 + wid * 2048 + 1024]);
    GLOBAL_LDS16(b3 + kt * 32, &Bs[buf * 8192 + wid * 2048 + 1536]);
  };

  f32x4 acc[8][4];
  #pragma unroll
  for (int i = 0; i < 8; ++i)
    #pragma unroll
    for (int j = 0; j < 4; ++j) acc[i][j] = (f32x4){0.f, 0.f, 0.f, 0.f};

#define FTILE(BUF, STG) do { \
    bf16x8 af[8], bv[4]; \
    _Pragma("unroll") for (int mf = 0; mf < 8; ++mf) \
      af[mf] = *(const bf16x8*)&As[(BUF) * 4096 + (mf * 16 + l15) * 32 + colS]; \
    _Pragma("unroll") for (int nf = 0; nf < 4; ++nf) \
      bv[nf] = *(const bf16x8*)&Bs[(BUF) * 8192 + (wn * 64 + nf * 16 + l15) * 32 + colS]; \
    STG; \
    __builtin_amdgcn_s_setprio(1); \
    _Pragma("unroll") for (int mf = 0; mf < 8; ++mf) \
      _Pragma("unroll") for (int nf = 0; nf < 4; ++nf) \
        acc[mf][nf] = __builtin_amdgcn_mfma_f32_16x16x32_bf16( \
            af[mf], bv[nf], acc[mf][nf], 0, 0, 0); \
    __builtin_amdgcn_s_setprio(0); \
  } while (0)

  stage(0, 0); stage(1, 1);
  for (int it = 0; it < 7; ++it) {
    int T = 3 * it;
    GATE(6); FTILE(0, stage(2, T + 2));
    GATE(6); FTILE(1, stage(0, T + 3));
    GATE(6); FTILE(2, stage(1, T + 4));
  }
  GATE(6); FTILE(0, stage(2, 23));
  GATE(6); FTILE(1, {});
  GATE(0); FTILE(2, {});
#undef FTILE

  int r0 = bm * 128, c0 = bn * 256 + wn * 64;
  #pragma unroll
  for (int mf = 0; mf < 8; ++mf)
    #pragma unroll
    for (int nf = 0; nf < 4; ++nf) {
      int col = c0 + nf * 16 + l15;
      #pragma unroll
      for (int r = 0; r < 4; ++r) {
        int row = r0 + mf * 16 + hi * 4 + r;
        Cf[(size_t)row * D_MODEL + col] =
            acc[mf][nf][r] + resid[(size_t)row * D_MODEL + col];
      }
    }
}

extern "C" void kernel_launch(void* const* d_in, const int* in_sizes, int n_in,
                              void* d_out, int out_size, void* d_ws, size_t ws_size,
                              hipStream_t stream) {
  const float* x     = (const float*)d_in[0];
  const float* gamma = (const float*)d_in[1];
  const float* beta  = (const float*)d_in[2];
  const float* w_qkv = (const float*)d_in[3];
  const float* w_out = (const float*)d_in[4];
  float* out = (float*)d_out;

  char* ws = (char*)d_ws;
  size_t off = 0;
  auto alloc = [&](size_t bytes) -> void* {
    void* p = ws + off; off += (bytes + 255) & ~(size_t)255; return p;
  };
  unsigned short* xn    = (unsigned short*)alloc((size_t)ROWS * D_MODEL * 2);  // reused as qhat
  unsigned short* qb    = (unsigned short*)alloc((size_t)ROWS * D_MODEL * 2);
  unsigned short* kTb   = (unsigned short*)alloc((size_t)64 * 96 * SEQ * 2);
  unsigned short* vTb   = (unsigned short*)alloc((size_t)64 * 96 * SEQ * 2);
  unsigned short* wqkvT = (unsigned short*)alloc((size_t)N3 * D_MODEL * 2);
  unsigned short* woutT = (unsigned short*)alloc((size_t)D_MODEL * D_MODEL * 2);
  float* kvp            = (float*)alloc((size_t)512 * 96 * 112 * 4);
  unsigned short* kvN   = (unsigned short*)alloc((size_t)64 * 96 * 96 * 2);
  float* ksumf          = (float*)alloc((size_t)64 * 96 * 4);
  unsigned short* Mt    = (unsigned short*)alloc((size_t)BATCH * 768 * 768 * 2);

  prep_kernel<<<2304 + ROWS / 4, 256, 0, stream>>>(w_qkv, w_out, wqkvT, woutT,
                                                   x, gamma, beta, xn);
  gemm_qkv_w_kernel<<<(ROWS / 128) * (N3 / 256), 256, 0, stream>>>(xn, wqkvT, qb, kTb, vTb);
  kvagg3_kernel<<<512, 256, 0, stream>>>(kTb, vTb, kvp);
  kvreduce2_kernel<<<(64 * 96 * 112 + 255) / 256, 256, 0, stream>>>(kvp, kvN, ksumf);
  mid_kernel<<<192 + ROWS / 64, 256, 0, stream>>>(kvN, woutT, Mt, qb, ksumf, xn);
  gemm_fin_kernel<<<(ROWS / 128) * 3, 256, 0, stream>>>(xn, Mt, x, out);
}